// Round 1
// baseline (676.771 us; speedup 1.0000x reference)
//
#include <hip/hip_runtime.h>
#include <math.h>

// EPG-X MT TSE simulation, MI355X.
// One wave (64 lanes) per voxel; lane = k-group (0..35 used).
// State per lane: Fp, Fm, Za, Zb in registers. Shift = __shfl_up/down.
// All 32 echoes staged in LDS [144][33] (pad to break bank conflicts),
// flushed at the end as contiguous per-voxel chunks (coalesced 256B stores).

#define GAMC 0.2675221

// kpp table from _epg_dims(33); steps use KPP[1..32]
__device__ __constant__ int KPP_tab_unused[1]; // (kept none; we use constexpr below)

__global__ __launch_bounds__(64) void epg_tse_kernel(
    const float* __restrict__ theta,
    const float* __restrict__ b1t,
    const float* __restrict__ R1av,
    const float* __restrict__ R2av,
    const float* __restrict__ fv,
    const float* __restrict__ kav,
    const float* __restrict__ kbv,
    const float* __restrict__ z0v,
    const void* esp_p,
    const void* g_p,
    float* __restrict__ out,
    int im)
{
    constexpr int KPP[33] = {3,5,7,9,11,13,15,17,19,21,23,25,27,29,31,33,35,
                             33,31,29,27,25,23,21,19,17,15,13,11,9,7,5,3};

    __shared__ float stage[144 * 33];   // 19008 B: [row][echo], stride 33 floats

    const int v = blockIdx.x;
    if (v >= im) return;
    const int k = threadIdx.x;          // group index; k>=36 are helper zero lanes

    // ---- scalar inputs (ESP, G): sniff int32 vs float32 bit pattern ----
    int ei = *(const int*)esp_p;
    float esp = (ei > 0 && ei < 1000000) ? (float)ei : *(const float*)esp_p;
    int gi = *(const int*)g_p;
    float gg = (gi > 0 && gi < 1000000) ? (float)gi : *(const float*)g_p;

    // ---- per-voxel parameters ----
    const float R1 = R1av[v];
    const float R2 = R2av[v];
    const float f  = fv[v];
    const float ka = kav[v];
    const float kb = kbv[v];

    const float hesp = 0.5f * esp;              // 4
    const float E2 = expf(-hesp * R2);

    // M = 0.5*ESP*Lam ; closed-form 2x2 expm (real eigenvalues, ka*kb>0)
    const float M00 = hesp * (-R1 - ka);
    const float M01 = hesp * kb;
    const float M10 = hesp * ka;
    const float M11 = hesp * (-R1 - kb);
    const float mu = 0.5f * (M00 + M11);
    const float dl = 0.5f * (M00 - M11);
    float q2 = dl * dl + M01 * M10;
    float q = sqrtf(fmaxf(q2, 1e-30f));
    const float s1 = expm1f(q);
    const float s2m = expm1f(-q);
    const float chq = 1.0f + 0.5f * (s1 + s2m);
    const float shq_q = (0.5f * (s1 - s2m)) / q;
    const float emu = expf(mu);
    const float X00 = emu * (chq + shq_q * dl);
    const float X11 = emu * (chq - shq_q * dl);
    const float X01 = emu * (shq_q * M01);
    const float X10 = emu * (shq_q * M10);

    // Zoff = (Xi - I) * Lam^{-1} CL   (Cramer 2x2 solve, matches reference)
    const float L00 = -R1 - ka, L01 = kb, L10 = ka, L11 = -R1 - kb;
    const float CL0 = (1.0f - f) * R1;
    const float CL1 = f * R1;
    const float det = L00 * L11 - L01 * L10;
    const float sol0 = (L11 * CL0 - L01 * CL1) / det;
    const float sol1 = (L00 * CL1 - L10 * CL0) / det;
    const float b2 = (X00 - 1.0f) * sol0 + X01 * sol1;
    const float b3 = X10 * sol0 + (X11 - 1.0f) * sol1;
    const float bb2 = (k == 0) ? b2 : 0.0f;
    const float bb3 = (k == 0) ? b3 : 0.0f;

    // ---- RF matrices (voxel-uniform) ----
    const float wtc = (float)(M_PI * (double)GAMC * (double)GAMC) * (gg * 0.001f);
    const float a0 = fabsf(theta[0]);
    const float WT0 = wtc * b1t[0];
    float ch0 = cosf(0.5f * a0); const float c2e = ch0 * ch0;
    float sh0 = sinf(0.5f * a0); const float s2e = sh0 * sh0;
    const float ce = cosf(a0), se = sinf(a0);
    const float e0 = expf(-WT0);

    const float a1 = fabsf(theta[1]);
    const float WT1 = wtc * b1t[1];
    float ch1 = cosf(0.5f * a1); const float c2r = ch1 * ch1;
    float sh1 = sinf(0.5f * a1); const float s2r = sh1 * sh1;
    const float cr = cosf(a1), sr = sinf(a1);
    const float hsr = 0.5f * sr;
    const float e1 = expf(-WT1);

    // ---- initial state ----
    float fp = 0.0f, fm = 0.0f, za = 0.0f, zb = 0.0f;
    if (k == 0) { za = z0v[2 * v]; zb = z0v[2 * v + 1]; }

    // Excitation applied to group 0 only; all other lanes are zero so
    // applying it everywhere maps 0 -> 0 (exact).
    {
        float tfp = c2e * fp - s2e * fm + se * za;
        float tfm = -s2e * fp + c2e * fm + se * za;
        float tza = -0.5f * se * fp - 0.5f * se * fm + ce * za;
        float tzb = e0 * zb;
        fp = tfp; fm = tfm; za = tza; zb = tzb;
        // relax
        float rp = E2 * fp, rm = E2 * fm;
        float ra = X00 * za + X01 * zb;
        float rb = X10 * za + X11 * zb;
        // shift with m = N (only the zero-flag at row 141 applies)
        float A = __shfl_up(rp, 1, 64);
        float C = __shfl_down(rm, 1, 64);
        fp = (k == 0) ? C : A;
        fm = (k + 1 < 36) ? C : 0.0f;
        za = ra + bb2;
        zb = rb + bb3;
    }

    // ---- 32 refocusing steps ----
#pragma unroll
    for (int i = 0; i < 32; ++i) {
        const int Ki = KPP[i + 1];            // compile-time literal
        const bool act = (k < Ki);

        // RF refocus on active groups
        float tfp = c2r * fp + s2r * fm + sr * za;
        float tfm = s2r * fp + c2r * fm - sr * za;
        float tza = -hsr * fp + hsr * fm + cr * za;
        float tzb = e1 * zb;
        fp = act ? tfp : fp;
        fm = act ? tfm : fm;
        za = act ? tza : za;
        zb = act ? tzb : zb;

        // relax + shift -> Fcol (recorded echo)
        float rp = E2 * fp, rm = E2 * fm;
        float ra = X00 * za + X01 * zb;
        float rb = X10 * za + X11 * zb;
        float A = __shfl_up(rp, 1, 64);
        float C = __shfl_down(rm, 1, 64);
        float cp = (k == 0) ? C : A;
        float cm = (k + 1 < Ki) ? C : 0.0f;
        float ca = ra + bb2;
        float cb = rb + bb3;
        cp = act ? cp : 0.0f;
        cm = act ? cm : 0.0f;
        ca = act ? ca : 0.0f;
        cb = act ? cb : 0.0f;

        // stage Fcol: rows 4k..4k+3 at echo i
        if (k < 36) {
            const int base = k * 132;          // 4 rows * 33 stride
            stage[base + i]       = cp;
            stage[base + 33 + i]  = cm;
            stage[base + 66 + i]  = ca;
            stage[base + 99 + i]  = cb;
        }

        // relax + shift on Fcol -> next FF (frozen for k >= Ki)
        float rp2 = E2 * cp, rm2 = E2 * cm;
        float ra2 = X00 * ca + X01 * cb;
        float rb2 = X10 * ca + X11 * cb;
        float A2 = __shfl_up(rp2, 1, 64);
        float C2 = __shfl_down(rm2, 1, 64);
        float nfp = (k == 0) ? C2 : A2;
        float nfm = (k + 1 < Ki) ? C2 : 0.0f;
        float nza = ra2 + bb2;
        float nzb = rb2 + bb3;
        fp = act ? nfp : fp;
        fm = act ? nfm : fm;
        za = act ? nza : za;
        zb = act ? nzb : zb;
    }

    __syncthreads();

    // ---- flush: coalesced contiguous writes per voxel ----
    const int lane = threadIdx.x;
    const int e = lane & 31;
    const int half = lane >> 5;

    float* F0 = out;                                        // [im][32]
    float* Fn = out + (size_t)im * 32;                      // [im][69][32]
    float* Zn = out + (size_t)im * 32 + (size_t)im * 69 * 32; // [im][36][32][2]

    // F0[v][e] = Fcol row 0
    if (lane < 32) {
        F0[(size_t)v * 32 + lane] = stage[lane];            // row 0, stride 33, row*33=0
    }

    // Fn: j=0..32 -> Fm[33-j] (row 133-4j); j=33 -> row 0; j=34..68 -> Fp[j-33]
#pragma unroll
    for (int t = 0; t < 35; ++t) {
        const int j = 2 * t + half;
        if (j < 69) {
            int row;
            if (j <= 32)      row = 133 - 4 * j;
            else if (j == 33) row = 0;
            else              row = 4 * (j - 33);
            Fn[(size_t)v * 2208 + j * 32 + e] = stage[row * 33 + e];
        }
    }

    // Zn[v][kk][e][c] = Fcol row 4kk+2+c ; lane = 2e+c
#pragma unroll
    for (int kk = 0; kk < 36; ++kk) {
        const int row = 4 * kk + 2 + (lane & 1);
        Zn[(size_t)v * 2304 + kk * 64 + lane] = stage[row * 33 + (lane >> 1)];
    }
}

extern "C" void kernel_launch(void* const* d_in, const int* in_sizes, int n_in,
                              void* d_out, int out_size, void* d_ws, size_t ws_size,
                              hipStream_t stream) {
    const float* theta = (const float*)d_in[0];
    const float* b1t   = (const float*)d_in[1];
    const float* R1a   = (const float*)d_in[2];
    const float* R2a   = (const float*)d_in[3];
    const float* f     = (const float*)d_in[4];
    const float* ka    = (const float*)d_in[5];
    const float* kb    = (const float*)d_in[6];
    const float* z0    = (const float*)d_in[7];
    const void* esp    = d_in[8];
    const void* g      = d_in[9];
    const int im = in_sizes[2];   // R1a element count = number of voxels

    epg_tse_kernel<<<im, 64, 0, stream>>>(theta, b1t, R1a, R2a, f, ka, kb, z0,
                                          esp, g, (float*)d_out, im);
}